// Round 7
// baseline (126.256 us; speedup 1.0000x reference)
//
#include <hip/hip_runtime.h>
#include <hip/hip_bf16.h>

#define TT   1024
#define NF   32
#define NB   128
#define HID  16
#define KK   5
#define DD   4
#define FPAD 24
#define XROW (FPAD + TT + FPAD)          // 1072 bf16 per (f,b) row
#define WPO  ((size_t)NF * NB * XROW)    // ushort offset of weight pack in ws

typedef short short8   __attribute__((ext_vector_type(8)));
typedef short short8_u __attribute__((ext_vector_type(8), aligned(4)));
typedef float floatx4  __attribute__((ext_vector_type(4)));

__device__ inline ushort f2bf(float f) {
    union { float f; uint u; } v; v.f = f;
    uint r = v.u + 0x7fffu + ((v.u >> 16) & 1u);
    return (ushort)(r >> 16);
}
__device__ inline uint cvt_pk_bf16(float lo, float hi) {
    uint r;
    asm("v_cvt_pk_bf16_f32 %0, %1, %2" : "=v"(r) : "v"(lo), "v"(hi));
    return r;
}

// ---- pre-kernel: transpose x to (F,B,XROW) bf16 + weight fragment pack ----
__global__ __launch_bounds__(256) void prep_k(
    const float* __restrict__ x, const float* __restrict__ w1,
    const float* __restrict__ w2, ushort* __restrict__ xhi,
    ushort* __restrict__ wpack)
{
    const int tc  = blockIdx.x;
    const int b   = blockIdx.y;
    const int tid = threadIdx.x;

    if (tc == 4) {
        if (b >= NF || tid >= 64) return;
        const int f = b, lane = tid;
        const int g = lane >> 4, crow = lane & 15;
        short8 a0 = {0,0,0,0,0,0,0,0}, a1 = a0, af[3] = {a0, a0, a0};
        if (g == 0) {
            const float* w1f = w1 + (size_t)f * HID * KK + crow * KK;
            #pragma unroll
            for (int j = 0; j < 8; ++j) {
                if (j < 5)           a0[j] = (short)f2bf(w1f[j]);
                if (j >= 1 && j < 6) a1[j] = (short)f2bf(w1f[j - 1]);
            }
        }
        const int cin0 = (g & 1) * 8, dk = g >> 1;
        const float* w2f = w2 + (size_t)f * HID * HID * KK;
        #pragma unroll
        for (int p = 0; p < 3; ++p) {
            int k = 2 * p + dk;
            #pragma unroll
            for (int j = 0; j < 8; ++j)
                af[p][j] = (k < KK) ? (short)f2bf(w2f[crow * (HID * KK) + (cin0 + j) * KK + k]) : (short)0;
        }
        short8* dst = (short8*)wpack + ((size_t)f * 64 + lane) * 5;
        dst[0] = a0; dst[1] = a1; dst[2] = af[0]; dst[3] = af[1]; dst[4] = af[2];
        return;
    }

    // transpose chunk tc (256 t's) of batch b, all 32 fields
    __shared__ float ls[256 * 40];

    const float4* xb = (const float4*)(x + ((size_t)b * TT + tc * 256) * NF);
    #pragma unroll
    for (int i = 0; i < 8; ++i) {
        int v = tid + 256 * i;
        float4 val = xb[v];
        int tl = v >> 3, f0 = 4 * (v & 7);
        int col = f0 ^ (4 * (tl >> 5));        // XOR-swizzled column (2-way free)
        *(float4*)&ls[tl * 40 + col] = val;
    }
    __syncthreads();

    // register transpose: thread owns (f = tid>>3, tb = tid&7) -> 32 t's of one f
    const int f  = tid >> 3, tb = tid & 7;
    const int col = f ^ (4 * tb);
    uint hbu[16];
    #pragma unroll
    for (int m = 0; m < 32; m += 2) {
        float v0 = ls[(tb * 32 + m)     * 40 + col];
        float v1 = ls[(tb * 32 + m + 1) * 40 + col];
        hbu[m >> 1] = cvt_pk_bf16(v0, v1);
    }
    size_t di = (size_t)(f * NB + b) * XROW + FPAD + tc * 256 + tb * 32;
    uint4* dh = (uint4*)(xhi + di);
    #pragma unroll
    for (int q = 0; q < 4; ++q)
        dh[q] = make_uint4(hbu[4*q], hbu[4*q+1], hbu[4*q+2], hbu[4*q+3]);

    if (tc == 0) {
        for (int i = tid; i < NF * FPAD; i += 256) {
            int fz = i / FPAD, e = i % FPAD;
            xhi[(size_t)(fz * NB + b) * XROW + e] = 0;
        }
    } else if (tc == 3) {
        for (int i = tid; i < NF * FPAD; i += 256) {
            int fz = i / FPAD, e = i % FPAD;
            xhi[(size_t)(fz * NB + b) * XROW + FPAD + TT + e] = 0;
        }
    }
}

// ---- fused branch kernel: all-MFMA conv1+conv2, half-tiles, 8 blocks/CU ----
// Per wave: segment of 256 cols as 2 passes of 128 cols; per-pass tile =
// 160 rows x 16 cin bf16 (5 KB), swizzled (64B line = 2 rows,
// chunk = ((r&1)<<1 | half) ^ (line&3)).
__global__ __launch_bounds__(256, 8) void fused_kernel(
    const ushort* __restrict__ xhi, const ushort* __restrict__ wpack,
    const float* __restrict__ b1, const float* __restrict__ b2,
    const float* __restrict__ pw, const float* __restrict__ pb,
    float* __restrict__ out)
{
    const int f = blockIdx.x & 31;
    const int b = blockIdx.x >> 5;
    const int tid  = threadIdx.x;
    const int wave = tid >> 6;
    const int lane = tid & 63;
    const int g    = lane >> 4;
    const int crow = lane & 15;
    const bool odd = (crow & 1) != 0;

    __shared__ __align__(64) ushort tiles[4][2560];   // 80 lines/wave
    float* pool_lds = (float*)&tiles[0][0];            // overlaid; used after barrier
    ushort* tile = tiles[wave];

    // ---- packed weights: 5 coalesced 16B loads ----
    const short8* wl = (const short8*)wpack + ((size_t)f * 64 + lane) * 5;
    const short8 a0 = wl[0], a1 = wl[1];
    const short8 af0 = wl[2], af1 = wl[3], af2 = wl[4];
    const float4 b1v = *(const float4*)(b1 + f * HID + 4 * g);
    const float4 b2v = *(const float4*)(b2 + f * HID + 4 * g);
    const int dk = g >> 1;

    // ---- lane-constant swizzled LDS bases ----
    const int woffbase = (crow >> 1) * 32
                       + (((((crow & 1) << 1) | (g >> 1)) ^ ((crow >> 1) & 3)) << 3)
                       + ((g & 1) << 2);
    ushort* wdst = tile + woffbase;
    const int E  = crow + dk + 14;
    const int Ch = ((E & 1) << 1) | (g & 1);
    const ushort* tp0 = tile + ((E >> 1) + 0) * 32 + ((Ch ^ (((E >> 1) + 0) & 3)) << 3);
    const ushort* tp1 = tile + ((E >> 1) + 1) * 32 + ((Ch ^ (((E >> 1) + 1) & 3)) << 3);
    const ushort* tp2 = tile + ((E >> 1) + 2) * 32 + ((Ch ^ (((E >> 1) + 2) & 3)) << 3);

    const ushort* xh = xhi + (size_t)(f * NB + b) * XROW;

    float psum[4] = {0.f, 0.f, 0.f, 0.f};

    #pragma unroll
    for (int pass = 0; pass < 2; ++pass) {
        const int tp = wave * 256 + pass * 128;

        // ---- prefetch 10 conv1 B-fragments ----
        const ushort* xbase = xh + (tp - 16 + (crow & ~1) + (FPAD - 2));
        short8 bh[10];
        #pragma unroll
        for (int us = 0; us < 10; ++us)
            bh[us] = *(const short8_u*)(xbase + 16 * us);

        // ---- conv1: 10 subtiles -> tile rows [0,160) (t = tp-16+r) ----
        #pragma unroll
        for (int us = 0; us < 10; ++us) {
            const int tbase = tp - 16 + 16 * us;
            uint2 wv;
            if (tbase < 0 || tbase >= TT) {       // wave-uniform zero halo
                wv = make_uint2(0u, 0u);
            } else {
                floatx4 ae = {b1v.x, b1v.y, b1v.z, b1v.w};
                floatx4 ao = ae;
                ae = __builtin_amdgcn_mfma_f32_16x16x32_bf16(a0, bh[us], ae, 0, 0, 0);
                ao = __builtin_amdgcn_mfma_f32_16x16x32_bf16(a1, bh[us], ao, 0, 0, 0);
                float h0  = fmaxf(odd ? ao[0] : ae[0], 0.f);
                float h1v = fmaxf(odd ? ao[1] : ae[1], 0.f);
                float h2  = fmaxf(odd ? ao[2] : ae[2], 0.f);
                float h3  = fmaxf(odd ? ao[3] : ae[3], 0.f);
                wv = make_uint2(cvt_pk_bf16(h0, h1v), cvt_pk_bf16(h2, h3));
            }
            *(uint2*)(wdst + 256 * us) = wv;
        }

        // ---- conv2 + relu + pool accumulate ----
        #pragma unroll
        for (int ti = 0; ti < 2; ++ti) {
            #pragma unroll
            for (int st = 0; st < 4; ++st) {
                const int off = ti * 1024 + st * 256;
                floatx4 acc = {b2v.x, b2v.y, b2v.z, b2v.w};
                acc = __builtin_amdgcn_mfma_f32_16x16x32_bf16(af0, *(const short8*)(tp0 + off), acc, 0, 0, 0);
                acc = __builtin_amdgcn_mfma_f32_16x16x32_bf16(af1, *(const short8*)(tp1 + off), acc, 0, 0, 0);
                acc = __builtin_amdgcn_mfma_f32_16x16x32_bf16(af2, *(const short8*)(tp2 + off), acc, 0, 0, 0);
                #pragma unroll
                for (int rr = 0; rr < 4; ++rr) psum[rr] += fmaxf(acc[rr], 0.f);
            }
        }
    }

    __syncthreads();   // all tile reads/writes done; safe to overlay pool

    // ---- pool reduce across the 16 col-lanes of each group ----
    #pragma unroll
    for (int rr = 0; rr < 4; ++rr) {
        float v = psum[rr];
        v += __shfl_xor(v, 1, 64);
        v += __shfl_xor(v, 2, 64);
        v += __shfl_xor(v, 4, 64);
        v += __shfl_xor(v, 8, 64);
        if (crow == 0) pool_lds[(4 * g + rr) * DD + wave] = v * (1.f / 256.f);
    }
    __syncthreads();

    // ---- final GEMV ----
    if (tid < DD) {
        const float* pwr = pw + ((size_t)f * DD + tid) * (HID * DD);
        float o = pb[f * DD + tid];
        #pragma unroll
        for (int i = 0; i < HID * DD; ++i) o = fmaf(pwr[i], pool_lds[i], o);
        out[((size_t)b * NF + f) * DD + tid] = o;
    }
}

extern "C" void kernel_launch(void* const* d_in, const int* in_sizes, int n_in,
                              void* d_out, int out_size, void* d_ws, size_t ws_size,
                              hipStream_t stream) {
    const float* x  = (const float*)d_in[0];
    // d_in[1] = lengths (unused by reference)
    const float* w1 = (const float*)d_in[2];
    const float* b1 = (const float*)d_in[3];
    const float* w2 = (const float*)d_in[4];
    const float* b2 = (const float*)d_in[5];
    const float* pw = (const float*)d_in[6];
    const float* pb = (const float*)d_in[7];
    float* out = (float*)d_out;

    ushort* xhi   = (ushort*)d_ws;
    ushort* wpack = xhi + WPO;

    prep_k<<<dim3(5, NB), dim3(256), 0, stream>>>(x, w1, w2, xhi, wpack);
    fused_kernel<<<dim3(NF * NB), dim3(256), 0, stream>>>(xhi, wpack, b1, b2, pw, pb, out);
}

// Round 8
// 43.042 us; speedup vs baseline: 2.9333x; 2.9333x over previous
//
#include <hip/hip_runtime.h>
#include <hip/hip_bf16.h>

#define TT   1024
#define NF   32
#define NB   128
#define HID  16
#define KK   5
#define DD   4
#define FPAD 24
#define XROW (FPAD + TT + FPAD)          // 1072 bf16 per (f,b) row
#define WPO  ((size_t)NF * NB * XROW)    // ushort offset of weight pack in ws

typedef short short8   __attribute__((ext_vector_type(8)));
typedef short short8_u __attribute__((ext_vector_type(8), aligned(4)));
typedef float floatx4  __attribute__((ext_vector_type(4)));

__device__ inline ushort f2bf(float f) {
    union { float f; uint u; } v; v.f = f;
    uint r = v.u + 0x7fffu + ((v.u >> 16) & 1u);
    return (ushort)(r >> 16);
}
__device__ inline uint cvt_pk_bf16(float lo, float hi) {
    uint r;
    asm("v_cvt_pk_bf16_f32 %0, %1, %2" : "=v"(r) : "v"(lo), "v"(hi));
    return r;
}

// ---- pre-kernel: transpose x to (F,B,XROW) bf16 + weight fragment pack ----
__global__ __launch_bounds__(256) void prep_k(
    const float* __restrict__ x, const float* __restrict__ w1,
    const float* __restrict__ w2, ushort* __restrict__ xhi,
    ushort* __restrict__ wpack)
{
    const int tc  = blockIdx.x;
    const int b   = blockIdx.y;
    const int tid = threadIdx.x;

    if (tc == 4) {
        if (b >= NF || tid >= 64) return;
        const int f = b, lane = tid;
        const int g = lane >> 4, crow = lane & 15;
        short8 a0 = {0,0,0,0,0,0,0,0}, a1 = a0, af[3] = {a0, a0, a0};
        if (g == 0) {
            const float* w1f = w1 + (size_t)f * HID * KK + crow * KK;
            #pragma unroll
            for (int j = 0; j < 8; ++j) {
                if (j < 5)           a0[j] = (short)f2bf(w1f[j]);
                if (j >= 1 && j < 6) a1[j] = (short)f2bf(w1f[j - 1]);
            }
        }
        const int cin0 = (g & 1) * 8, dk = g >> 1;
        const float* w2f = w2 + (size_t)f * HID * HID * KK;
        #pragma unroll
        for (int p = 0; p < 3; ++p) {
            int k = 2 * p + dk;
            #pragma unroll
            for (int j = 0; j < 8; ++j)
                af[p][j] = (k < KK) ? (short)f2bf(w2f[crow * (HID * KK) + (cin0 + j) * KK + k]) : (short)0;
        }
        short8* dst = (short8*)wpack + ((size_t)f * 64 + lane) * 5;
        dst[0] = a0; dst[1] = a1; dst[2] = af[0]; dst[3] = af[1]; dst[4] = af[2];
        return;
    }

    // transpose chunk tc (256 t's) of batch b, all 32 fields
    __shared__ float ls[256 * 40];

    const float4* xb = (const float4*)(x + ((size_t)b * TT + tc * 256) * NF);
    #pragma unroll
    for (int i = 0; i < 8; ++i) {
        int v = tid + 256 * i;
        float4 val = xb[v];
        int tl = v >> 3, f0 = 4 * (v & 7);
        int col = f0 ^ (4 * (tl >> 5));        // XOR-swizzled column (2-way free)
        *(float4*)&ls[tl * 40 + col] = val;
    }
    __syncthreads();

    // register transpose: thread owns (f = tid>>3, tb = tid&7) -> 32 t's of one f
    const int f  = tid >> 3, tb = tid & 7;
    const int col = f ^ (4 * tb);
    uint hbu[16];
    #pragma unroll
    for (int m = 0; m < 32; m += 2) {
        float v0 = ls[(tb * 32 + m)     * 40 + col];
        float v1 = ls[(tb * 32 + m + 1) * 40 + col];
        hbu[m >> 1] = cvt_pk_bf16(v0, v1);
    }
    size_t di = (size_t)(f * NB + b) * XROW + FPAD + tc * 256 + tb * 32;
    uint4* dh = (uint4*)(xhi + di);
    #pragma unroll
    for (int q = 0; q < 4; ++q)
        dh[q] = make_uint4(hbu[4*q], hbu[4*q+1], hbu[4*q+2], hbu[4*q+3]);

    if (tc == 0) {
        for (int i = tid; i < NF * FPAD; i += 256) {
            int fz = i / FPAD, e = i % FPAD;
            xhi[(size_t)(fz * NB + b) * XROW + e] = 0;
        }
    } else if (tc == 3) {
        for (int i = tid; i < NF * FPAD; i += 256) {
            int fz = i / FPAD, e = i % FPAD;
            xhi[(size_t)(fz * NB + b) * XROW + FPAD + TT + e] = 0;
        }
    }
}

// ---- fused branch kernel: all-MFMA conv1+conv2, 4x64-col passes/wave ----
// Per pass: tile = 96 rows x 16 cin bf16 (3 KB/wave), swizzled
// (64B line = 2 rows, chunk = ((r&1)<<1 | half) ^ (line&3)).
// LDS addressing is pass-invariant; only the global x base moves.
__global__ __launch_bounds__(256, 4) void fused_kernel(
    const ushort* __restrict__ xhi, const ushort* __restrict__ wpack,
    const float* __restrict__ b1, const float* __restrict__ b2,
    const float* __restrict__ pw, const float* __restrict__ pb,
    float* __restrict__ out)
{
    const int f = blockIdx.x & 31;
    const int b = blockIdx.x >> 5;
    const int tid  = threadIdx.x;
    const int wave = tid >> 6;
    const int lane = tid & 63;
    const int g    = lane >> 4;
    const int crow = lane & 15;
    const bool odd = (crow & 1) != 0;

    __shared__ __align__(64) ushort tiles[4][1536];    // 48 lines/wave
    float* pool_lds = (float*)&tiles[0][0];             // overlaid; used after barrier
    ushort* tile = tiles[wave];

    // ---- packed weights: 5 coalesced 16B loads ----
    const short8* wl = (const short8*)wpack + ((size_t)f * 64 + lane) * 5;
    const short8 a0 = wl[0], a1 = wl[1];
    const short8 af0 = wl[2], af1 = wl[3], af2 = wl[4];
    const float4 b1v = *(const float4*)(b1 + f * HID + 4 * g);
    const float4 b2v = *(const float4*)(b2 + f * HID + 4 * g);
    const int dk = g >> 1;

    // ---- lane-constant swizzled LDS bases (pass-invariant) ----
    const int woffbase = (crow >> 1) * 32
                       + (((((crow & 1) << 1) | (g >> 1)) ^ ((crow >> 1) & 3)) << 3)
                       + ((g & 1) << 2);
    ushort* wdst = tile + woffbase;
    const int E  = crow + dk + 14;
    const int Ch = ((E & 1) << 1) | (g & 1);
    const ushort* tp0 = tile + ((E >> 1) + 0) * 32 + ((Ch ^ (((E >> 1) + 0) & 3)) << 3);
    const ushort* tp1 = tile + ((E >> 1) + 1) * 32 + ((Ch ^ (((E >> 1) + 1) & 3)) << 3);
    const ushort* tp2 = tile + ((E >> 1) + 2) * 32 + ((Ch ^ (((E >> 1) + 2) & 3)) << 3);

    const ushort* xh = xhi + (size_t)(f * NB + b) * XROW;

    float psum[4] = {0.f, 0.f, 0.f, 0.f};

    #pragma unroll 1
    for (int pass = 0; pass < 4; ++pass) {
        const int tp = wave * 256 + pass * 64;

        // ---- prefetch 6 conv1 B-fragments (1 base + imm offsets) ----
        const ushort* xbase = xh + (tp - 16 + (crow & ~1) + (FPAD - 2));
        short8 bh[6];
        #pragma unroll
        for (int us = 0; us < 6; ++us)
            bh[us] = *(const short8_u*)(xbase + 16 * us);

        // ---- conv1: 6 subtiles -> tile rows [0,96) (t = tp-16+r) ----
        #pragma unroll
        for (int us = 0; us < 6; ++us) {
            const int tbase = tp - 16 + 16 * us;
            uint2 wv;
            if (tbase < 0 || tbase >= TT) {       // wave-uniform zero halo
                wv = make_uint2(0u, 0u);
            } else {
                floatx4 ae = {b1v.x, b1v.y, b1v.z, b1v.w};
                floatx4 ao = ae;
                ae = __builtin_amdgcn_mfma_f32_16x16x32_bf16(a0, bh[us], ae, 0, 0, 0);
                ao = __builtin_amdgcn_mfma_f32_16x16x32_bf16(a1, bh[us], ao, 0, 0, 0);
                float h0  = fmaxf(odd ? ao[0] : ae[0], 0.f);
                float h1v = fmaxf(odd ? ao[1] : ae[1], 0.f);
                float h2  = fmaxf(odd ? ao[2] : ae[2], 0.f);
                float h3  = fmaxf(odd ? ao[3] : ae[3], 0.f);
                wv = make_uint2(cvt_pk_bf16(h0, h1v), cvt_pk_bf16(h2, h3));
            }
            *(uint2*)(wdst + 256 * us) = wv;
        }

        // ---- conv2 + relu + pool accumulate (4 subtiles of 16 cols) ----
        #pragma unroll
        for (int st = 0; st < 4; ++st) {
            const int off = st * 256;
            floatx4 acc = {b2v.x, b2v.y, b2v.z, b2v.w};
            acc = __builtin_amdgcn_mfma_f32_16x16x32_bf16(af0, *(const short8*)(tp0 + off), acc, 0, 0, 0);
            acc = __builtin_amdgcn_mfma_f32_16x16x32_bf16(af1, *(const short8*)(tp1 + off), acc, 0, 0, 0);
            acc = __builtin_amdgcn_mfma_f32_16x16x32_bf16(af2, *(const short8*)(tp2 + off), acc, 0, 0, 0);
            #pragma unroll
            for (int rr = 0; rr < 4; ++rr) psum[rr] += fmaxf(acc[rr], 0.f);
        }
    }

    __syncthreads();   // all tile reads/writes done; safe to overlay pool

    // ---- pool reduce across the 16 col-lanes of each group ----
    #pragma unroll
    for (int rr = 0; rr < 4; ++rr) {
        float v = psum[rr];
        v += __shfl_xor(v, 1, 64);
        v += __shfl_xor(v, 2, 64);
        v += __shfl_xor(v, 4, 64);
        v += __shfl_xor(v, 8, 64);
        if (crow == 0) pool_lds[(4 * g + rr) * DD + wave] = v * (1.f / 256.f);
    }
    __syncthreads();

    // ---- final GEMV ----
    if (tid < DD) {
        const float* pwr = pw + ((size_t)f * DD + tid) * (HID * DD);
        float o = pb[f * DD + tid];
        #pragma unroll
        for (int i = 0; i < HID * DD; ++i) o = fmaf(pwr[i], pool_lds[i], o);
        out[((size_t)b * NF + f) * DD + tid] = o;
    }
}

extern "C" void kernel_launch(void* const* d_in, const int* in_sizes, int n_in,
                              void* d_out, int out_size, void* d_ws, size_t ws_size,
                              hipStream_t stream) {
    const float* x  = (const float*)d_in[0];
    // d_in[1] = lengths (unused by reference)
    const float* w1 = (const float*)d_in[2];
    const float* b1 = (const float*)d_in[3];
    const float* w2 = (const float*)d_in[4];
    const float* b2 = (const float*)d_in[5];
    const float* pw = (const float*)d_in[6];
    const float* pb = (const float*)d_in[7];
    float* out = (float*)d_out;

    ushort* xhi   = (ushort*)d_ws;
    ushort* wpack = xhi + WPO;

    prep_k<<<dim3(5, NB), dim3(256), 0, stream>>>(x, w1, w2, xhi, wpack);
    fused_kernel<<<dim3(NF * NB), dim3(256), 0, stream>>>(xhi, wpack, b1, b2, pw, pb, out);
}